// Round 6
// baseline (430.021 us; speedup 1.0000x reference)
//
#include <hip/hip_runtime.h>
#include <hip/hip_fp16.h>

// ---------------------------------------------------------------------------
// GCN 2-layer forward. Pipeline:
//   bktcnt : 128-bucket histogram of dst>>10 (LDS-staged)
//   bktscan: exclusive scan -> bucket bases; rowptr[N]=E
//   binA   : bin edges by bucket into stage[{dstLocal<<17|src, ew}]
//            (LDS rank + one cursor bump per bucket per 2048-edge chunk ->
//             ~128B sequential bursts per bucket)
//   hist   : per-bucket LDS histogram (1024 nodes, packed u64 cnt|fixpt(sum ew)
//            + srcA count) -> dinv, rowptr (bucket base + local scan), mid
//            (start of src>=N/2 sub-segment). No global scan, no atomics.
//   sort   : per-bucket scatter stage -> edata[{src, norm}] via LDS cursors;
//            each node's segment partitioned [rowptr,mid)=srcA, [mid,next)=srcB
//   gemm   : 64x64 tile, 4x4 micro-tile, fp32 compute, fp16 H store
//   pullA  : agg = h_self*dinv^2 + bias + sum over srcA edges (6.4MB gather set)
//   pullB  : agg += sum over srcB edges (other 6.4MB gather set)
// Assumes N <= 131072 (17-bit src, 128 buckets x 1024), max weighted indegree
// < 4096 (fixed-point field). Holds here (N=100k, E=1.6M, ew in (0,1)).
// ---------------------------------------------------------------------------

constexpr float FXS     = 1048576.0f;    // 2^20 fixed-point scale
constexpr float FXS_INV = 1.0f / 1048576.0f;
constexpr int   NBKT    = 128;           // dst buckets (1024 nodes each)

__global__ __launch_bounds__(256) void k_bktcnt(const int* __restrict__ dst,
                                                int* __restrict__ bktsize, int nE) {
    __shared__ int cnt[NBKT];
    const int tid = threadIdx.x;
    if (tid < NBKT) cnt[tid] = 0;
    __syncthreads();
    int stride = gridDim.x * blockDim.x;
    for (int e = blockIdx.x * blockDim.x + tid; e < nE; e += stride)
        atomicAdd(&cnt[dst[e] >> 10], 1);
    __syncthreads();
    if (tid < NBKT && cnt[tid] > 0) atomicAdd(&bktsize[tid], cnt[tid]);
}

__global__ __launch_bounds__(NBKT) void k_bktscan(const int* __restrict__ bktsize,
                                                  int* __restrict__ bktbase,
                                                  int* __restrict__ bktcur,
                                                  int* __restrict__ rowptr,
                                                  int N, int E) {
    __shared__ int v[NBKT];
    const int t = threadIdx.x;
    int s = bktsize[t];
    v[t] = s;
    __syncthreads();
    for (int off = 1; off < NBKT; off <<= 1) {
        int x = (t >= off) ? v[t - off] : 0;
        __syncthreads();
        v[t] += x;
        __syncthreads();
    }
    int excl = v[t] - s;
    bktbase[t] = excl;
    bktcur[t] = excl;
    if (t == 0) rowptr[N] = E;
}

// Bin edges into bucket-grouped staging. Chunk = 2048 edges per block-iter:
// LDS rank within (chunk,bucket) + one global cursor bump per bucket.
__global__ __launch_bounds__(256) void k_binA(const int* __restrict__ src,
                                              const int* __restrict__ dst,
                                              const float* __restrict__ ew,
                                              int* __restrict__ bktcur,
                                              int2* __restrict__ stage, int nE) {
    __shared__ int cnt[NBKT], gbase[NBKT];
    const int tid = threadIdx.x;
    const int nchunks = (nE + 2047) >> 11;
    for (int c = blockIdx.x; c < nchunks; c += gridDim.x) {
        const int base = c << 11;
        if (tid < NBKT) cnt[tid] = 0;
        __syncthreads();
        int bkt[8], rank[8], pck[8];
        float w[8];
        #pragma unroll
        for (int j = 0; j < 8; ++j) {
            int e = base + j * 256 + tid;
            bkt[j] = -1;
            if (e < nE) {
                int t = dst[e];
                w[j] = ew[e];
                bkt[j] = t >> 10;
                pck[j] = ((t & 1023) << 17) | src[e];
                rank[j] = atomicAdd(&cnt[bkt[j]], 1);
            }
        }
        __syncthreads();
        if (tid < NBKT && cnt[tid] > 0) gbase[tid] = atomicAdd(&bktcur[tid], cnt[tid]);
        __syncthreads();
        #pragma unroll
        for (int j = 0; j < 8; ++j)
            if (bkt[j] >= 0)
                stage[gbase[bkt[j]] + rank[j]] = make_int2(pck[j], __float_as_int(w[j]));
        __syncthreads();
    }
}

// Per-bucket: degree histogram + srcA count in LDS -> dinv, rowptr, mid.
__global__ __launch_bounds__(256) void k_hist(const int2* __restrict__ stage,
                                              const int* __restrict__ bktbase,
                                              const int* __restrict__ bktsize,
                                              float* __restrict__ dinv,
                                              int* __restrict__ rowptr,
                                              int* __restrict__ mid,
                                              int N, int N2) {
    __shared__ unsigned long long hh[1024];
    __shared__ int ha[1024];
    __shared__ int psum[256];
    const int tid = threadIdx.x;
    const int b = blockIdx.x;
    for (int i = tid; i < 1024; i += 256) { hh[i] = 0ull; ha[i] = 0; }
    __syncthreads();
    const int start = bktbase[b], len = bktsize[b];
    for (int i = start + tid; i < start + len; i += 256) {
        int2 en = stage[i];
        int local = ((unsigned)en.x) >> 17;
        int s = en.x & 131071;
        unsigned long long fx = __float2uint_rn(__int_as_float(en.y) * FXS);
        atomicAdd(&hh[local], (1ull << 32) | fx);
        if (s < N2) atomicAdd(&ha[local], 1);
    }
    __syncthreads();
    // local exclusive scan over 1024 counts (4 per thread)
    int c[4];
    int s4 = 0;
    #pragma unroll
    for (int j = 0; j < 4; ++j) { c[j] = (int)(hh[4 * tid + j] >> 32); s4 += c[j]; }
    psum[tid] = s4;
    __syncthreads();
    for (int off = 1; off < 256; off <<= 1) {
        int x = (tid >= off) ? psum[tid - off] : 0;
        __syncthreads();
        psum[tid] += x;
        __syncthreads();
    }
    int run = psum[tid] - s4 + start;
    #pragma unroll
    for (int j = 0; j < 4; ++j) {
        int local = 4 * tid + j;
        int g = (b << 10) + local;
        if (g < N) {
            unsigned long long v = hh[local];
            float deg = 1.0f + (float)(v & 0xffffffffull) * FXS_INV;
            dinv[g] = rsqrtf(deg);
            rowptr[g] = run;
            mid[g] = run + ha[local];
        }
        run += c[j];
    }
}

// Per-bucket scatter to final CSR position via LDS cursors; computes norm.
__global__ __launch_bounds__(256) void k_sort(const int2* __restrict__ stage,
                                              const int* __restrict__ bktbase,
                                              const int* __restrict__ bktsize,
                                              const int* __restrict__ rowptr,
                                              const int* __restrict__ mid,
                                              const float* __restrict__ dinv,
                                              int2* __restrict__ edata,
                                              int N, int N2) {
    __shared__ int curA[1024], curB[1024];
    __shared__ float df[1024];
    const int tid = threadIdx.x;
    const int b = blockIdx.x;
    for (int i = tid; i < 1024; i += 256) {
        int g = (b << 10) + i;
        if (g < N) {
            curA[i] = rowptr[g];
            curB[i] = mid[g];
            df[i] = dinv[g];
        }
    }
    __syncthreads();
    const int start = bktbase[b], len = bktsize[b];
    for (int i = start + tid; i < start + len; i += 256) {
        int2 en = stage[i];
        int local = ((unsigned)en.x) >> 17;
        int s = en.x & 131071;
        float nr = dinv[s] * __int_as_float(en.y) * df[local];
        int pos = (s < N2) ? atomicAdd(&curA[local], 1) : atomicAdd(&curB[local], 1);
        edata[pos] = make_int2(s, __float_as_int(nr));
    }
}

// ---------------------------------------------------------------------------
// Tiled GEMM: H16[n][64] = half( (RELU?max(X,0):X)[n][K] @ W[64][K]^T )
// ---------------------------------------------------------------------------
template <int K, bool RELU>
__global__ __launch_bounds__(256, 4) void k_gemm(const float* __restrict__ X,
                                                 const float* __restrict__ W,
                                                 __half* __restrict__ H, int n) {
    constexpr int BK = 64, BK4 = 16;
    constexpr int XP = 68, WP = 68;
    __shared__ float Xs[64 * XP];
    __shared__ float Ws[BK * WP];
    const int tid = threadIdx.x;
    const int bn0 = blockIdx.x * 64;
    const int tx = tid & 15, ty = tid >> 4;
    const int f0 = 4 * tx, nl = 4 * ty;

    float acc[4][4] = {};

    for (int kb = 0; kb < K; kb += BK) {
        #pragma unroll
        for (int it = 0; it < 4; ++it) {
            int idx = tid + it * 256;
            int node = idx >> 4, k4 = idx & 15;
            int g = bn0 + node;
            float4 v = make_float4(0.f, 0.f, 0.f, 0.f);
            if (g < n)
                v = *reinterpret_cast<const float4*>(X + (size_t)g * K + kb + 4 * k4);
            if (RELU) {
                v.x = fmaxf(v.x, 0.f); v.y = fmaxf(v.y, 0.f);
                v.z = fmaxf(v.z, 0.f); v.w = fmaxf(v.w, 0.f);
            }
            *reinterpret_cast<float4*>(&Xs[node * XP + 4 * k4]) = v;
        }
        #pragma unroll
        for (int it = 0; it < 4; ++it) {
            int idx = tid + it * 256;
            int feat = idx >> 4, k4 = idx & 15;
            float4 v = *reinterpret_cast<const float4*>(W + feat * K + kb + 4 * k4);
            Ws[(4 * k4 + 0) * WP + feat] = v.x;
            Ws[(4 * k4 + 1) * WP + feat] = v.y;
            Ws[(4 * k4 + 2) * WP + feat] = v.z;
            Ws[(4 * k4 + 3) * WP + feat] = v.w;
        }
        __syncthreads();

        #pragma unroll 4
        for (int k4 = 0; k4 < BK4; ++k4) {
            float4 xv[4], wv[4];
            #pragma unroll
            for (int i = 0; i < 4; ++i)
                xv[i] = *reinterpret_cast<const float4*>(&Xs[(nl + i) * XP + 4 * k4]);
            #pragma unroll
            for (int c = 0; c < 4; ++c)
                wv[c] = *reinterpret_cast<const float4*>(&Ws[(4 * k4 + c) * WP + f0]);
            #pragma unroll
            for (int i = 0; i < 4; ++i) {
                const float xc[4] = {xv[i].x, xv[i].y, xv[i].z, xv[i].w};
                #pragma unroll
                for (int c = 0; c < 4; ++c) {
                    acc[i][0] = fmaf(xc[c], wv[c].x, acc[i][0]);
                    acc[i][1] = fmaf(xc[c], wv[c].y, acc[i][1]);
                    acc[i][2] = fmaf(xc[c], wv[c].z, acc[i][2]);
                    acc[i][3] = fmaf(xc[c], wv[c].w, acc[i][3]);
                }
            }
        }
        __syncthreads();
    }

    #pragma unroll
    for (int i = 0; i < 4; ++i) {
        int g = bn0 + nl + i;
        if (g < n) {
            union { __half h[4]; uint2 u; } cv;
            cv.h[0] = __float2half_rn(acc[i][0]);
            cv.h[1] = __float2half_rn(acc[i][1]);
            cv.h[2] = __float2half_rn(acc[i][2]);
            cv.h[3] = __float2half_rn(acc[i][3]);
            *reinterpret_cast<uint2*>(H + (size_t)g * 64 + f0) = cv.u;
        }
    }
}

// Pull over fp16 H, src-range split. Pass A (FIN=false): edges [rowptr,mid)
// (src < N/2), acc init = self-loop + bias. Pass B (FIN=true): edges
// [mid, rowptr+1) (src >= N/2), acc init = partial from pass A.
template <bool FIN>
__global__ __launch_bounds__(256) void k_pull(const int* __restrict__ rowptr,
                                              const int* __restrict__ mid,
                                              const int2* __restrict__ edata,
                                              const __half* __restrict__ H,
                                              const float* __restrict__ dinv,
                                              const float* __restrict__ bias,
                                              float* __restrict__ OUT, int n) {
    const int wave = threadIdx.x >> 6, lane = threadIdx.x & 63;
    const float b = FIN ? 0.f : bias[lane];
    for (int node = blockIdx.x * 4 + wave; node < n; node += gridDim.x * 4) {
        const int rs = FIN ? mid[node] : rowptr[node];
        const int re = FIN ? rowptr[node + 1] : mid[node];
        float acc;
        if (FIN) {
            acc = OUT[((size_t)node << 6) + lane];
        } else {
            const float di = dinv[node];
            acc = fmaf(__half2float(H[((size_t)node << 6) + lane]), di * di, b);
        }
        int e = rs;
        for (; e + 16 <= re; e += 16) {
            int2 ed[16];
            float hv[16];
            #pragma unroll
            for (int j = 0; j < 16; ++j) ed[j] = edata[e + j];
            #pragma unroll
            for (int j = 0; j < 16; ++j)
                hv[j] = __half2float(H[((size_t)ed[j].x << 6) + lane]);
            #pragma unroll
            for (int j = 0; j < 16; ++j) acc = fmaf(hv[j], __int_as_float(ed[j].y), acc);
        }
        for (; e + 4 <= re; e += 4) {
            int2 ed[4];
            float hv[4];
            #pragma unroll
            for (int j = 0; j < 4; ++j) ed[j] = edata[e + j];
            #pragma unroll
            for (int j = 0; j < 4; ++j)
                hv[j] = __half2float(H[((size_t)ed[j].x << 6) + lane]);
            #pragma unroll
            for (int j = 0; j < 4; ++j) acc = fmaf(hv[j], __int_as_float(ed[j].y), acc);
        }
        for (; e < re; ++e) {
            int2 ed = edata[e];
            acc = fmaf(__half2float(H[((size_t)ed.x << 6) + lane]),
                       __int_as_float(ed.y), acc);
        }
        OUT[((size_t)node << 6) + lane] = acc;
    }
}

extern "C" void kernel_launch(void* const* d_in, const int* in_sizes, int n_in,
                              void* d_out, int out_size, void* d_ws, size_t ws_size,
                              hipStream_t stream) {
    const float* x  = (const float*)d_in[0];
    const int*   ei = (const int*)d_in[1];
    const float* ew = (const float*)d_in[2];
    const float* W1 = (const float*)d_in[3];
    const float* b1 = (const float*)d_in[4];
    const float* W2 = (const float*)d_in[5];
    const float* b2 = (const float*)d_in[6];

    const int N = in_sizes[0] / 128;
    const int E = in_sizes[2];
    const int N2 = N >> 1;
    const int* src = ei;
    const int* dst = ei + E;

    float* ws = (float*)d_ws;
    size_t o = 0;
    float* dinv    = ws + o;           o += N;
    int*   rowptr  = (int*)(ws + o);   o += (size_t)N + 1;
    int*   mid     = (int*)(ws + o);   o += N;
    int*   bktsize = (int*)(ws + o);   o += NBKT;
    int*   bktbase = (int*)(ws + o);   o += NBKT;
    int*   bktcur  = (int*)(ws + o);   o += NBKT;
    o = (o + 1) & ~(size_t)1;                              // 8B align
    int2*  edata   = (int2*)(ws + o);  o += 2 * (size_t)E;
    int2*  stage   = (int2*)(ws + o);  o += 2 * (size_t)E; // aliased by h16
    __half* h16    = (__half*)stage;                       // N*64 halves, dead stage
    float* agg1    = ws + o;           o += 64 * (size_t)N;
    float* out     = (float*)d_out;

    dim3 blk(256);

    hipMemsetAsync(bktsize, 0, NBKT * sizeof(int), stream);
    k_bktcnt<<<256, blk, 0, stream>>>(dst, bktsize, E);
    k_bktscan<<<1, NBKT, 0, stream>>>(bktsize, bktbase, bktcur, rowptr, N, E);
    k_binA<<<512, blk, 0, stream>>>(src, dst, ew, bktcur, stage, E);
    k_hist<<<NBKT, blk, 0, stream>>>(stage, bktbase, bktsize, dinv, rowptr, mid, N, N2);
    k_sort<<<NBKT, blk, 0, stream>>>(stage, bktbase, bktsize, rowptr, mid, dinv,
                                     edata, N, N2);

    const int gemm_blocks = (N + 63) / 64;
    // Layer 1
    k_gemm<128, false><<<gemm_blocks, blk, 0, stream>>>(x, W1, h16, N);
    k_pull<false><<<2048, blk, 0, stream>>>(rowptr, mid, edata, h16, dinv, b1, agg1, N);
    k_pull<true><<<2048, blk, 0, stream>>>(rowptr, mid, edata, h16, dinv, b1, agg1, N);
    // Layer 2
    k_gemm<64, true><<<gemm_blocks, blk, 0, stream>>>(agg1, W2, h16, N);
    k_pull<false><<<2048, blk, 0, stream>>>(rowptr, mid, edata, h16, dinv, b2, out, N);
    k_pull<true><<<2048, blk, 0, stream>>>(rowptr, mid, edata, h16, dinv, b2, out, N);
}

// Round 7
// 305.545 us; speedup vs baseline: 1.4074x; 1.4074x over previous
//
#include <hip/hip_runtime.h>
#include <hip/hip_fp16.h>

// ---------------------------------------------------------------------------
// GCN 2-layer forward. Pipeline:
//   bktcnt : 128-bucket histogram of dst>>10 (LDS-staged)
//   bktscan: exclusive scan -> bucket bases; rowptr[N]=E
//   binA   : bin edges by bucket into stage[{dstLocal<<17|src, ew}]
//   hist   : per-bucket LDS degree histogram -> dinv, rowptr (base+local scan)
//   sort   : per-bucket scatter stage -> edata[{src, norm}] via LDS cursors
//   winstart: per-256-edge-window binary search of rowptr
//   gemm   : 64x64 tile, 4x4 micro-tile, fp32 compute; epilogue writes fp16 H
//            AND fp32 AGG-init = h*dinv^2 + bias (self-loop fused)
//   pull   : edge-major merge-path: each wave owns one 256-edge window staged
//            in LDS, walks rowptr, adds into AGG (interior: plain RMW,
//            boundary nodes: atomicAdd). Single pass per layer.
// Assumes N <= 131072 (17-bit src, 128 buckets x 1024), weighted indegree
// < 4096 (fixed-point field). Holds here (N=100k, E=1.6M, ew in (0,1)).
// ---------------------------------------------------------------------------

constexpr float FXS     = 1048576.0f;    // 2^20 fixed-point scale
constexpr float FXS_INV = 1.0f / 1048576.0f;
constexpr int   NBKT    = 128;           // dst buckets (1024 nodes each)
constexpr int   PW      = 256;           // edges per pull-wave window

__global__ __launch_bounds__(256) void k_bktcnt(const int* __restrict__ dst,
                                                int* __restrict__ bktsize, int nE) {
    __shared__ int cnt[NBKT];
    const int tid = threadIdx.x;
    if (tid < NBKT) cnt[tid] = 0;
    __syncthreads();
    int stride = gridDim.x * blockDim.x;
    for (int e = blockIdx.x * blockDim.x + tid; e < nE; e += stride)
        atomicAdd(&cnt[dst[e] >> 10], 1);
    __syncthreads();
    if (tid < NBKT && cnt[tid] > 0) atomicAdd(&bktsize[tid], cnt[tid]);
}

__global__ __launch_bounds__(NBKT) void k_bktscan(const int* __restrict__ bktsize,
                                                  int* __restrict__ bktbase,
                                                  int* __restrict__ bktcur,
                                                  int* __restrict__ rowptr,
                                                  int N, int E) {
    __shared__ int v[NBKT];
    const int t = threadIdx.x;
    int s = bktsize[t];
    v[t] = s;
    __syncthreads();
    for (int off = 1; off < NBKT; off <<= 1) {
        int x = (t >= off) ? v[t - off] : 0;
        __syncthreads();
        v[t] += x;
        __syncthreads();
    }
    int excl = v[t] - s;
    bktbase[t] = excl;
    bktcur[t] = excl;
    if (t == 0) rowptr[N] = E;
}

// Bin edges into bucket-grouped staging. Chunk = 2048 edges per block-iter:
// LDS rank within (chunk,bucket) + one global cursor bump per bucket.
__global__ __launch_bounds__(256) void k_binA(const int* __restrict__ src,
                                              const int* __restrict__ dst,
                                              const float* __restrict__ ew,
                                              int* __restrict__ bktcur,
                                              int2* __restrict__ stage, int nE) {
    __shared__ int cnt[NBKT], gbase[NBKT];
    const int tid = threadIdx.x;
    const int nchunks = (nE + 2047) >> 11;
    for (int c = blockIdx.x; c < nchunks; c += gridDim.x) {
        const int base = c << 11;
        if (tid < NBKT) cnt[tid] = 0;
        __syncthreads();
        int bkt[8], rank[8], pck[8];
        float w[8];
        #pragma unroll
        for (int j = 0; j < 8; ++j) {
            int e = base + j * 256 + tid;
            bkt[j] = -1;
            if (e < nE) {
                int t = dst[e];
                w[j] = ew[e];
                bkt[j] = t >> 10;
                pck[j] = ((t & 1023) << 17) | src[e];
                rank[j] = atomicAdd(&cnt[bkt[j]], 1);
            }
        }
        __syncthreads();
        if (tid < NBKT && cnt[tid] > 0) gbase[tid] = atomicAdd(&bktcur[tid], cnt[tid]);
        __syncthreads();
        #pragma unroll
        for (int j = 0; j < 8; ++j)
            if (bkt[j] >= 0)
                stage[gbase[bkt[j]] + rank[j]] = make_int2(pck[j], __float_as_int(w[j]));
        __syncthreads();
    }
}

// Per-bucket degree histogram in LDS -> dinv, rowptr (bucket base + local scan).
__global__ __launch_bounds__(256) void k_hist(const int2* __restrict__ stage,
                                              const int* __restrict__ bktbase,
                                              const int* __restrict__ bktsize,
                                              float* __restrict__ dinv,
                                              int* __restrict__ rowptr, int N) {
    __shared__ unsigned long long hh[1024];
    __shared__ int psum[256];
    const int tid = threadIdx.x;
    const int b = blockIdx.x;
    for (int i = tid; i < 1024; i += 256) hh[i] = 0ull;
    __syncthreads();
    const int start = bktbase[b], len = bktsize[b];
    for (int i = start + tid; i < start + len; i += 256) {
        int2 en = stage[i];
        int local = ((unsigned)en.x) >> 17;
        unsigned long long fx = __float2uint_rn(__int_as_float(en.y) * FXS);
        atomicAdd(&hh[local], (1ull << 32) | fx);
    }
    __syncthreads();
    int c[4];
    int s4 = 0;
    #pragma unroll
    for (int j = 0; j < 4; ++j) { c[j] = (int)(hh[4 * tid + j] >> 32); s4 += c[j]; }
    psum[tid] = s4;
    __syncthreads();
    for (int off = 1; off < 256; off <<= 1) {
        int x = (tid >= off) ? psum[tid - off] : 0;
        __syncthreads();
        psum[tid] += x;
        __syncthreads();
    }
    int run = psum[tid] - s4 + start;
    #pragma unroll
    for (int j = 0; j < 4; ++j) {
        int local = 4 * tid + j;
        int g = (b << 10) + local;
        if (g < N) {
            unsigned long long v = hh[local];
            float deg = 1.0f + (float)(v & 0xffffffffull) * FXS_INV;
            dinv[g] = rsqrtf(deg);
            rowptr[g] = run;
        }
        run += c[j];
    }
}

// Per-bucket scatter to final CSR position via LDS cursors; computes norm.
__global__ __launch_bounds__(256) void k_sort(const int2* __restrict__ stage,
                                              const int* __restrict__ bktbase,
                                              const int* __restrict__ bktsize,
                                              const int* __restrict__ rowptr,
                                              const float* __restrict__ dinv,
                                              int2* __restrict__ edata, int N) {
    __shared__ int cur[1024];
    __shared__ float df[1024];
    const int tid = threadIdx.x;
    const int b = blockIdx.x;
    for (int i = tid; i < 1024; i += 256) {
        int g = (b << 10) + i;
        if (g < N) {
            cur[i] = rowptr[g];
            df[i] = dinv[g];
        }
    }
    __syncthreads();
    const int start = bktbase[b], len = bktsize[b];
    for (int i = start + tid; i < start + len; i += 256) {
        int2 en = stage[i];
        int local = ((unsigned)en.x) >> 17;
        int s = en.x & 131071;
        float nr = dinv[s] * __int_as_float(en.y) * df[local];
        int pos = atomicAdd(&cur[local], 1);
        edata[pos] = make_int2(s, __float_as_int(nr));
    }
}

// For each PW-edge window: first node (largest n with rowptr[n] <= w*PW).
__global__ __launch_bounds__(256) void k_winstart(const int* __restrict__ rowptr,
                                                  int* __restrict__ winstart,
                                                  int nW, int N) {
    int w = blockIdx.x * blockDim.x + threadIdx.x;
    if (w >= nW) return;
    int target = w * PW;
    int lo = 0, hi = N - 1;
    while (lo < hi) {
        int m = (lo + hi + 1) >> 1;
        if (rowptr[m] <= target) lo = m; else hi = m - 1;
    }
    winstart[w] = lo;
}

// ---------------------------------------------------------------------------
// Tiled GEMM: H16 = half(X'@W^T), AGG = (X'@W^T)*dinv^2 + bias  (X'=relu?(X))
// ---------------------------------------------------------------------------
template <int K, bool RELU>
__global__ __launch_bounds__(256, 4) void k_gemm(const float* __restrict__ X,
                                                 const float* __restrict__ W,
                                                 const float* __restrict__ dinv,
                                                 const float* __restrict__ bias,
                                                 __half* __restrict__ H,
                                                 float* __restrict__ AGG, int n) {
    constexpr int BK = 64, BK4 = 16;
    constexpr int XP = 68, WP = 68;
    __shared__ float Xs[64 * XP];
    __shared__ float Ws[BK * WP];
    const int tid = threadIdx.x;
    const int bn0 = blockIdx.x * 64;
    const int tx = tid & 15, ty = tid >> 4;
    const int f0 = 4 * tx, nl = 4 * ty;

    float acc[4][4] = {};

    for (int kb = 0; kb < K; kb += BK) {
        #pragma unroll
        for (int it = 0; it < 4; ++it) {
            int idx = tid + it * 256;
            int node = idx >> 4, k4 = idx & 15;
            int g = bn0 + node;
            float4 v = make_float4(0.f, 0.f, 0.f, 0.f);
            if (g < n)
                v = *reinterpret_cast<const float4*>(X + (size_t)g * K + kb + 4 * k4);
            if (RELU) {
                v.x = fmaxf(v.x, 0.f); v.y = fmaxf(v.y, 0.f);
                v.z = fmaxf(v.z, 0.f); v.w = fmaxf(v.w, 0.f);
            }
            *reinterpret_cast<float4*>(&Xs[node * XP + 4 * k4]) = v;
        }
        #pragma unroll
        for (int it = 0; it < 4; ++it) {
            int idx = tid + it * 256;
            int feat = idx >> 4, k4 = idx & 15;
            float4 v = *reinterpret_cast<const float4*>(W + feat * K + kb + 4 * k4);
            Ws[(4 * k4 + 0) * WP + feat] = v.x;
            Ws[(4 * k4 + 1) * WP + feat] = v.y;
            Ws[(4 * k4 + 2) * WP + feat] = v.z;
            Ws[(4 * k4 + 3) * WP + feat] = v.w;
        }
        __syncthreads();

        #pragma unroll 4
        for (int k4 = 0; k4 < BK4; ++k4) {
            float4 xv[4], wv[4];
            #pragma unroll
            for (int i = 0; i < 4; ++i)
                xv[i] = *reinterpret_cast<const float4*>(&Xs[(nl + i) * XP + 4 * k4]);
            #pragma unroll
            for (int c = 0; c < 4; ++c)
                wv[c] = *reinterpret_cast<const float4*>(&Ws[(4 * k4 + c) * WP + f0]);
            #pragma unroll
            for (int i = 0; i < 4; ++i) {
                const float xc[4] = {xv[i].x, xv[i].y, xv[i].z, xv[i].w};
                #pragma unroll
                for (int c = 0; c < 4; ++c) {
                    acc[i][0] = fmaf(xc[c], wv[c].x, acc[i][0]);
                    acc[i][1] = fmaf(xc[c], wv[c].y, acc[i][1]);
                    acc[i][2] = fmaf(xc[c], wv[c].z, acc[i][2]);
                    acc[i][3] = fmaf(xc[c], wv[c].w, acc[i][3]);
                }
            }
        }
        __syncthreads();
    }

    const float4 bs = *reinterpret_cast<const float4*>(bias + f0);
    #pragma unroll
    for (int i = 0; i < 4; ++i) {
        int g = bn0 + nl + i;
        if (g < n) {
            union { __half h[4]; uint2 u; } cv;
            cv.h[0] = __float2half_rn(acc[i][0]);
            cv.h[1] = __float2half_rn(acc[i][1]);
            cv.h[2] = __float2half_rn(acc[i][2]);
            cv.h[3] = __float2half_rn(acc[i][3]);
            *reinterpret_cast<uint2*>(H + ((size_t)g << 6) + f0) = cv.u;
            const float di = dinv[g];
            const float d2 = di * di;
            *reinterpret_cast<float4*>(AGG + ((size_t)g << 6) + f0) =
                make_float4(fmaf(acc[i][0], d2, bs.x), fmaf(acc[i][1], d2, bs.y),
                            fmaf(acc[i][2], d2, bs.z), fmaf(acc[i][3], d2, bs.w));
        }
    }
}

// Edge-major merge-path pull: wave owns edata[e0, e0+PW); stages window in
// LDS, walks rowptr, adds neighbor sums into AGG. Interior nodes: plain RMW
// (single owner). Window-boundary nodes: atomicAdd.
__global__ __launch_bounds__(256) void k_pull(const int* __restrict__ rowptr,
                                              const int* __restrict__ winstart,
                                              const int2* __restrict__ edata,
                                              const __half* __restrict__ H,
                                              float* __restrict__ AGG,
                                              int nW, int E) {
    __shared__ int2 eb[4][PW];
    const int wv = threadIdx.x >> 6, lane = threadIdx.x & 63;
    const int wid = blockIdx.x * 4 + wv;
    if (wid >= nW) return;
    const int e0 = wid * PW;
    const int e1 = min(e0 + PW, E);
    #pragma unroll
    for (int j = 0; j < PW / 64; ++j) {
        int e = e0 + j * 64 + lane;
        if (e < E) eb[wv][j * 64 + lane] = edata[e];
    }
    // wave-private LDS slice: same wave writes then reads; HW waitcnts order it.
    int n = winstart[wid];
    int rs = rowptr[n];
    int e = e0;
    while (e < e1) {
        const int re = rowptr[n + 1];
        const int seg_end = min(re, e1);
        if (seg_end > e) {
            float acc = 0.f;
            int i = e - e0;
            const int iend = seg_end - e0;
            for (; i + 8 <= iend; i += 8) {
                int2 ed[8];
                float hv[8];
                #pragma unroll
                for (int j = 0; j < 8; ++j) ed[j] = eb[wv][i + j];
                #pragma unroll
                for (int j = 0; j < 8; ++j)
                    hv[j] = __half2float(H[((size_t)ed[j].x << 6) + lane]);
                #pragma unroll
                for (int j = 0; j < 8; ++j)
                    acc = fmaf(hv[j], __int_as_float(ed[j].y), acc);
            }
            for (; i < iend; ++i) {
                int2 ed = eb[wv][i];
                acc = fmaf(__half2float(H[((size_t)ed.x << 6) + lane]),
                           __int_as_float(ed.y), acc);
            }
            const size_t idx = ((size_t)n << 6) + lane;
            if (rs >= e0 && re <= e1) AGG[idx] += acc;      // sole owner
            else atomicAdd(&AGG[idx], acc);                 // window boundary
        }
        e = seg_end;
        rs = re;
        ++n;
    }
}

extern "C" void kernel_launch(void* const* d_in, const int* in_sizes, int n_in,
                              void* d_out, int out_size, void* d_ws, size_t ws_size,
                              hipStream_t stream) {
    const float* x  = (const float*)d_in[0];
    const int*   ei = (const int*)d_in[1];
    const float* ew = (const float*)d_in[2];
    const float* W1 = (const float*)d_in[3];
    const float* b1 = (const float*)d_in[4];
    const float* W2 = (const float*)d_in[5];
    const float* b2 = (const float*)d_in[6];

    const int N = in_sizes[0] / 128;
    const int E = in_sizes[2];
    const int* src = ei;
    const int* dst = ei + E;
    const int nW = (E + PW - 1) / PW;

    float* ws = (float*)d_ws;
    size_t o = 0;
    float* dinv     = ws + o;           o += N;
    int*   rowptr   = (int*)(ws + o);   o += (size_t)N + 1;
    int*   winstart = (int*)(ws + o);   o += nW;
    int*   bktsize  = (int*)(ws + o);   o += NBKT;
    int*   bktbase  = (int*)(ws + o);   o += NBKT;
    int*   bktcur   = (int*)(ws + o);   o += NBKT;
    o = (o + 1) & ~(size_t)1;                              // 8B align
    int2*  edata    = (int2*)(ws + o);  o += 2 * (size_t)E;
    int2*  stage    = (int2*)(ws + o);  o += 2 * (size_t)E; // aliased by h16
    __half* h16     = (__half*)stage;                       // stage dead after sort
    float* agg1     = ws + o;           o += 64 * (size_t)N;
    float* out      = (float*)d_out;

    dim3 blk(256);

    hipMemsetAsync(bktsize, 0, NBKT * sizeof(int), stream);
    k_bktcnt<<<256, blk, 0, stream>>>(dst, bktsize, E);
    k_bktscan<<<1, NBKT, 0, stream>>>(bktsize, bktbase, bktcur, rowptr, N, E);
    k_binA<<<512, blk, 0, stream>>>(src, dst, ew, bktcur, stage, E);
    k_hist<<<NBKT, blk, 0, stream>>>(stage, bktbase, bktsize, dinv, rowptr, N);
    k_sort<<<NBKT, blk, 0, stream>>>(stage, bktbase, bktsize, rowptr, dinv, edata, N);
    k_winstart<<<(nW + 255) / 256, blk, 0, stream>>>(rowptr, winstart, nW, N);

    const int gemm_blocks = (N + 63) / 64;
    const int pull_blocks = (nW + 3) / 4;
    // Layer 1
    k_gemm<128, false><<<gemm_blocks, blk, 0, stream>>>(x, W1, dinv, b1, h16, agg1, N);
    k_pull<<<pull_blocks, blk, 0, stream>>>(rowptr, winstart, edata, h16, agg1, nW, E);
    // Layer 2
    k_gemm<64, true><<<gemm_blocks, blk, 0, stream>>>(agg1, W2, dinv, b2, h16, out, N);
    k_pull<<<pull_blocks, blk, 0, stream>>>(rowptr, winstart, edata, h16, out, nW, E);
}